// Round 1
// baseline (61334.888 us; speedup 1.0000x reference)
//
#include <hip/hip_runtime.h>
#include <hip/hip_fp16.h>

#define NPER   512
#define CDIM   256
#define BGRAPH 64
#define WINW   64
#define TPB    512
#define LISTCAP 256

// One workgroup per graph. Sequential scan (forward then backward) with
// __syncthreads() between stages. Ring buffer holds mlp(h) for the last 64
// updated nodes (all sources lie within a 64-node window by construction).
template<bool RING_WS>
__global__ __launch_bounds__(TPB)
void gnn_scan_kernel(const float* __restrict__ x,
                     const float* __restrict__ W1, const float* __restrict__ b1,
                     const float* __restrict__ W2, const float* __restrict__ b2,
                     const float* __restrict__ w_ih, const float* __restrict__ b_ih,
                     const float* __restrict__ w_hh, const float* __restrict__ b_hh,
                     const int* __restrict__ src_f, const int* __restrict__ gid_f,
                     const float* __restrict__ msk_f,
                     const int* __restrict__ src_b, const int* __restrict__ gid_b,
                     const float* __restrict__ msk_b,
                     int Kf, int Kb,
                     float* __restrict__ hx,      // d_out: (B*NPER, C) fp32
                     float* __restrict__ ring_ws) // d_ws (fp32 ring) or null
{
    const int b = blockIdx.x;
    const int t = threadIdx.x;

    __shared__ float sh_agg[CDIM];
    __shared__ float sh_hold[CDIM];
    __shared__ float sh_hnew[CDIM];
    __shared__ float sh_h1[CDIM];
    __shared__ float sh_gi[3 * CDIM];
    __shared__ float sh_gh[3 * CDIM];
    __shared__ int   sh_list[LISTCAP];
    __shared__ int   sh_cnt;
    // f16 fallback ring (32 KB) only instantiated when workspace too small
    __shared__ __half sh_ring_h[RING_WS ? 1 : (WINW * CDIM)];

    float* ringw = RING_WS ? (ring_ws + (size_t)b * WINW * CDIM) : (float*)nullptr;

    // ---- init: hx = x for this graph (d_out is poisoned each call) ----
    const size_t base = (size_t)b * NPER * CDIM;
    {
        const float4* x4  = (const float4*)(x + base);
        float4*       h4  = (float4*)(hx + base);
        for (int i = t; i < NPER * CDIM / 4; i += TPB) h4[i] = x4[i];
    }
    if (t == 0) sh_cnt = 0;
    __syncthreads();

    for (int pass = 0; pass < 2; ++pass) {
        const int*   srcA = pass ? src_b : src_f;
        const int*   gidA = pass ? gid_b : gid_f;
        const float* mskA = pass ? msk_b : msk_f;
        const int    K    = pass ? Kb : Kf;

        for (int step = 0; step < NPER; ++step) {
            const int node = pass ? (NPER - 1 - step) : step;

            // ---- s0: load h_old; scan pad row, compact same-graph edges ----
            if (t < CDIM / 4) {
                ((float4*)sh_hold)[t] =
                    ((const float4*)(hx + base + (size_t)node * CDIM))[t];
            }
            {
                const long rb = (long)step * K;
                for (int k = t; k < K; k += TPB) {
                    if (mskA[rb + k] != 0.0f && gidA[rb + k] == b) {
                        int pos = atomicAdd(&sh_cnt, 1);
                        if (pos < LISTCAP)
                            sh_list[pos] = srcA[rb + k] - b * NPER; // local node id
                    }
                }
            }
            __syncthreads();

            // ---- s1: agg[c] = sum over matched edges of ring[src][c] ----
            int cnt = sh_cnt;
            if (cnt > LISTCAP) cnt = LISTCAP;
            if (t < CDIM) {
                float a = 0.f;
                for (int e = 0; e < cnt; ++e) {
                    int slot = sh_list[e] & (WINW - 1);
                    a += RING_WS ? ringw[slot * CDIM + t]
                                 : __half2float(sh_ring_h[slot * CDIM + t]);
                }
                sh_agg[t] = a;
            }
            __syncthreads();

            // ---- s2: GRU gate GEMVs: 1536 rows of 256, 3 rows/thread ----
            #pragma unroll
            for (int d = 0; d < 3; ++d) {
                const int idx = t + d * TPB;
                const float* wrow;
                const float* inv;
                float bias;
                float* outp;
                if (idx < 3 * CDIM) {
                    wrow = w_ih + (size_t)idx * CDIM;
                    inv  = sh_agg;
                    bias = b_ih[idx];
                    outp = &sh_gi[idx];
                } else {
                    const int r = idx - 3 * CDIM;
                    wrow = w_hh + (size_t)r * CDIM;
                    inv  = sh_hold;
                    bias = b_hh[r];
                    outp = &sh_gh[r];
                }
                float acc = 0.f;
                const float4* w4 = (const float4*)wrow;
                const float4* i4 = (const float4*)inv;
                #pragma unroll 8
                for (int j = 0; j < CDIM / 4; ++j) {
                    float4 w = w4[j], v = i4[j];
                    acc += w.x * v.x + w.y * v.y + w.z * v.z + w.w * v.w;
                }
                *outp = acc + bias;
            }
            __syncthreads();

            // ---- s3: gate combine, write h_new ----
            if (t < CDIM) {
                float ir = sh_gi[t], iz = sh_gi[t + CDIM], in_ = sh_gi[t + 2 * CDIM];
                float hr = sh_gh[t], hz = sh_gh[t + CDIM], hn  = sh_gh[t + 2 * CDIM];
                float r = 1.0f / (1.0f + expf(-(ir + hr)));
                float z = 1.0f / (1.0f + expf(-(iz + hz)));
                float n = tanhf(in_ + r * hn);
                float hv = (1.0f - z) * n + z * sh_hold[t];
                sh_hnew[t] = hv;
                hx[base + (size_t)node * CDIM + t] = hv;
            }
            if (t == TPB - 1) sh_cnt = 0;  // reset for next step (barrier below)
            __syncthreads();

            // ---- s4: MLP layer 1 ----
            if (t < CDIM) {
                const float4* w4 = (const float4*)(W1 + (size_t)t * CDIM);
                const float4* i4 = (const float4*)sh_hnew;
                float acc = 0.f;
                #pragma unroll 8
                for (int j = 0; j < CDIM / 4; ++j) {
                    float4 w = w4[j], v = i4[j];
                    acc += w.x * v.x + w.y * v.y + w.z * v.z + w.w * v.w;
                }
                acc += b1[t];
                sh_h1[t] = acc > 0.f ? acc : 0.f;
            }
            __syncthreads();

            // ---- s5: MLP layer 2 -> ring[node & 63] ----
            if (t < CDIM) {
                const float4* w4 = (const float4*)(W2 + (size_t)t * CDIM);
                const float4* i4 = (const float4*)sh_h1;
                float acc = 0.f;
                #pragma unroll 8
                for (int j = 0; j < CDIM / 4; ++j) {
                    float4 w = w4[j], v = i4[j];
                    acc += w.x * v.x + w.y * v.y + w.z * v.z + w.w * v.w;
                }
                acc += b2[t];
                float h2 = acc > 0.f ? acc : 0.f;
                const int slot = node & (WINW - 1);
                if (RING_WS) ringw[slot * CDIM + t] = h2;
                else         sh_ring_h[slot * CDIM + t] = __float2half(h2);
            }
            __syncthreads();
        }
    }
}

extern "C" void kernel_launch(void* const* d_in, const int* in_sizes, int n_in,
                              void* d_out, int out_size, void* d_ws, size_t ws_size,
                              hipStream_t stream) {
    const float* x    = (const float*)d_in[0];
    const float* W1   = (const float*)d_in[1];
    const float* b1   = (const float*)d_in[2];
    const float* W2   = (const float*)d_in[3];
    const float* b2   = (const float*)d_in[4];
    const float* w_ih = (const float*)d_in[5];
    const float* b_ih = (const float*)d_in[6];
    const float* w_hh = (const float*)d_in[7];
    const float* b_hh = (const float*)d_in[8];
    const int*   src_f = (const int*)d_in[9];
    const int*   gid_f = (const int*)d_in[10];
    const float* msk_f = (const float*)d_in[11];
    const int*   src_b = (const int*)d_in[12];
    const int*   gid_b = (const int*)d_in[13];
    const float* msk_b = (const float*)d_in[14];

    const int Kf = in_sizes[9]  / NPER;
    const int Kb = in_sizes[12] / NPER;

    float* hx = (float*)d_out;

    const size_t ring_bytes = (size_t)BGRAPH * WINW * CDIM * sizeof(float); // 4 MB
    if (ws_size >= ring_bytes) {
        gnn_scan_kernel<true><<<BGRAPH, TPB, 0, stream>>>(
            x, W1, b1, W2, b2, w_ih, b_ih, w_hh, b_hh,
            src_f, gid_f, msk_f, src_b, gid_b, msk_b,
            Kf, Kb, hx, (float*)d_ws);
    } else {
        gnn_scan_kernel<false><<<BGRAPH, TPB, 0, stream>>>(
            x, W1, b1, W2, b2, w_ih, b_ih, w_hh, b_hh,
            src_f, gid_f, msk_f, src_b, gid_b, msk_b,
            Kf, Kb, hx, (float*)nullptr);
    }
}

// Round 3
// 33726.486 us; speedup vs baseline: 1.8186x; 1.8186x over previous
//
#include <hip/hip_runtime.h>

#define NPER 512
#define CDIM 256
#define BG   64
#define NB   128
#define TPB  256
#define NCL  8      // clusters (graph groups), cl = blockIdx % 8 (XCD-affine heuristic)
#define MPC  16     // members per cluster (channel groups)
#define GW   8      // graphs per cluster
#define CW   16     // channels per member
#define WST  132    // LDS k-major weight row stride (128 cols + 4 pad)
#define AST  10     // LDS k-major activation stride (8 graphs + 2 pad)
#define CAP  64     // per-graph edge list capacity

__global__ void init_bar(int* bar) { if (threadIdx.x < 512) bar[threadIdx.x] = 0; }

__device__ __forceinline__ void cluster_bar(int* cnt, int* gen, int target) {
    __syncthreads();
    if (threadIdx.x == 0) {
        __threadfence();
        int prev = __hip_atomic_fetch_add(cnt, 1, __ATOMIC_ACQ_REL, __HIP_MEMORY_SCOPE_AGENT);
        if (prev == MPC - 1) {
            __hip_atomic_store(cnt, 0, __ATOMIC_RELAXED, __HIP_MEMORY_SCOPE_AGENT);
            __hip_atomic_store(gen, target, __ATOMIC_RELEASE, __HIP_MEMORY_SCOPE_AGENT);
        } else {
            while (__hip_atomic_load(gen, __ATOMIC_RELAXED, __HIP_MEMORY_SCOPE_AGENT) < target)
                __builtin_amdgcn_s_sleep(1);
        }
        __threadfence();
    }
    __syncthreads();
}

__global__ __launch_bounds__(TPB, 1)
void gnn_fp32(const float* __restrict__ x,
              const float* __restrict__ W1g, const float* __restrict__ b1g,
              const float* __restrict__ W2g, const float* __restrict__ b2g,
              const float* __restrict__ wihg, const float* __restrict__ bihg,
              const float* __restrict__ whhg, const float* __restrict__ bhhg,
              const int* __restrict__ src_f, const int* __restrict__ gid_f,
              const float* __restrict__ msk_f,
              const int* __restrict__ src_b, const int* __restrict__ gid_b,
              const float* __restrict__ msk_b,
              int Kf, int Kb,
              float* __restrict__ hx,
              float* __restrict__ hnew, float* __restrict__ zb,
              float* __restrict__ agg, float* __restrict__ ring,
              int* bar)
{
    __shared__ float sh_w[256 * WST];    // k-major: cols 0-47 wih, 48-95 whh, 96-111 W1, 112-127 W2
    __shared__ float sh_act[256 * AST];  // k-major staged activations [k][g]
    __shared__ float sh_hold[256 * AST]; // k-major h_old [k][g]
    __shared__ float sh_gi[GW * 48];
    __shared__ float sh_gh[GW * 48];
    __shared__ int   sh_list[GW * CAP];
    __shared__ int   sh_cnt[GW];
    __shared__ float sh_bih[48], sh_bhh[48], sh_b1[CW], sh_b2[CW];

    const int tid   = threadIdx.x;
    const int cl    = blockIdx.x & 7;
    const int mb    = blockIdx.x >> 3;
    const int gb    = cl * GW;
    const int cbase = mb * CW;

    int* bcnt = bar + cl * 64;
    int* bgen = bar + cl * 64 + 16;
    float* ring_blk = ring + (size_t)blockIdx.x * 64 * GW * CW;

    // ---- stage weights (fp32) k-major into LDS, once ----
    for (int e = tid; e < 128 * 256; e += TPB) {
        int r = e >> 8, k = e & 255;   // thread tid has k==tid: coalesced global reads
        const float* sp; int grow;
        if (r < 48)       { sp = wihg; grow = (r >> 4) * CDIM + cbase + (r & 15); }
        else if (r < 96)  { sp = whhg; grow = ((r - 48) >> 4) * CDIM + cbase + ((r - 48) & 15); }
        else if (r < 112) { sp = W1g;  grow = cbase + (r - 96); }
        else              { sp = W2g;  grow = cbase + (r - 112); }
        sh_w[k * WST + r] = sp[(size_t)grow * CDIM + k];
    }
    if (tid < 48) {
        sh_bih[tid] = bihg[(tid >> 4) * CDIM + cbase + (tid & 15)];
        sh_bhh[tid] = bhhg[(tid >> 4) * CDIM + cbase + (tid & 15)];
    } else if (tid < 64) {
        sh_b1[tid - 48] = b1g[cbase + tid - 48];
        sh_b2[tid - 48] = b2g[cbase + tid - 48];
    }
    __syncthreads();

    int target = 1;
    float keep0 = 0.f;
    const int cg = tid >> 4;   // combine graph (tid<128)
    const int cc = tid & 15;   // combine channel

    const int sg = tid & 7;          // staging graph
    const int skb = (tid >> 3) * 8;  // staging k-base

    for (int pass = 0; pass < 2; ++pass) {
        const int* srcA   = pass ? src_b : src_f;
        const int* gidA   = pass ? gid_b : gid_f;
        const float* mskA = pass ? msk_b : msk_f;
        const int K = pass ? Kb : Kf;

        for (int s = 0; s < NPER; ++s) {
            const int node = pass ? (NPER - 1 - s) : s;
            const bool has_prev = !(pass == 0 && s == 0);
            const int prev = (s > 0) ? (pass ? node + 1 : node - 1) : (NPER - 1);

            // ================= P1: deferred hx write; stage hnew+hold; z=relu(W1 h)+gh =================
            if (has_prev && tid < 128)
                hx[((size_t)(gb + cg) * NPER + prev) * CDIM + cbase + cc] = keep0;
            {
                const float* hp = hnew + (size_t)(gb + sg) * CDIM + skb;
                float4 v0 = *(const float4*)hp, v1 = *(const float4*)(hp + 4);
                sh_act[(skb + 0) * AST + sg] = v0.x; sh_act[(skb + 1) * AST + sg] = v0.y;
                sh_act[(skb + 2) * AST + sg] = v0.z; sh_act[(skb + 3) * AST + sg] = v0.w;
                sh_act[(skb + 4) * AST + sg] = v1.x; sh_act[(skb + 5) * AST + sg] = v1.y;
                sh_act[(skb + 6) * AST + sg] = v1.z; sh_act[(skb + 7) * AST + sg] = v1.w;
                const float* op;
                if (pass == 0)      op = x + ((size_t)(gb + sg) * NPER + node) * CDIM + skb;
                else if (s == 0)    op = hnew + (size_t)(gb + sg) * CDIM + skb;  // fwd-final h(511)
                else                op = hx + ((size_t)(gb + sg) * NPER + node) * CDIM + skb;
                float4 h0 = *(const float4*)op, h1 = *(const float4*)(op + 4);
                sh_hold[(skb + 0) * AST + sg] = h0.x; sh_hold[(skb + 1) * AST + sg] = h0.y;
                sh_hold[(skb + 2) * AST + sg] = h0.z; sh_hold[(skb + 3) * AST + sg] = h0.w;
                sh_hold[(skb + 4) * AST + sg] = h1.x; sh_hold[(skb + 5) * AST + sg] = h1.y;
                sh_hold[(skb + 6) * AST + sg] = h1.z; sh_hold[(skb + 7) * AST + sg] = h1.w;
            }
            __syncthreads();

            // W1 GEMM (cols 96..111): 8 tiles x 2 rows, KS=32
            {
                const int tl = tid >> 5, ks = tid & 31;
                float acc0[8] = {}, acc1[8] = {};
                #pragma unroll
                for (int j = 0; j < 8; ++j) {
                    int k = ks + j * 32;
                    float2 w = *(const float2*)&sh_w[k * WST + 96 + tl * 2];
                    const float* ap = &sh_act[k * AST];
                    float2 a0 = *(const float2*)ap,       a1 = *(const float2*)(ap + 2);
                    float2 a2 = *(const float2*)(ap + 4), a3 = *(const float2*)(ap + 6);
                    float a[8] = {a0.x,a0.y,a1.x,a1.y,a2.x,a2.y,a3.x,a3.y};
                    #pragma unroll
                    for (int g = 0; g < 8; ++g) { acc0[g] += w.x * a[g]; acc1[g] += w.y * a[g]; }
                }
                #pragma unroll
                for (int m = 1; m < 32; m <<= 1)
                    #pragma unroll
                    for (int g = 0; g < 8; ++g) {
                        acc0[g] += __shfl_xor(acc0[g], m, 64);
                        acc1[g] += __shfl_xor(acc1[g], m, 64);
                    }
                if (ks < 8) {
                    int g = ks;
                    float v0 = acc0[g] + sh_b1[tl * 2];
                    float v1 = acc1[g] + sh_b1[tl * 2 + 1];
                    zb[(size_t)(gb + g) * CDIM + cbase + tl * 2]     = v0 > 0.f ? v0 : 0.f;
                    zb[(size_t)(gb + g) * CDIM + cbase + tl * 2 + 1] = v1 > 0.f ? v1 : 0.f;
                }
            }
            // gh GEMM (cols 48..95): 12 tiles x 4 rows, KS=16
            if (tid < 192) {
                const int tl = tid >> 4, ks = tid & 15;
                float acc[4][8] = {};
                #pragma unroll 4
                for (int j = 0; j < 16; ++j) {
                    int k = ks + j * 16;
                    float4 w = *(const float4*)&sh_w[k * WST + 48 + tl * 4];
                    const float* ap = &sh_hold[k * AST];
                    float2 a0 = *(const float2*)ap,       a1 = *(const float2*)(ap + 2);
                    float2 a2 = *(const float2*)(ap + 4), a3 = *(const float2*)(ap + 6);
                    float a[8] = {a0.x,a0.y,a1.x,a1.y,a2.x,a2.y,a3.x,a3.y};
                    #pragma unroll
                    for (int g = 0; g < 8; ++g) {
                        acc[0][g] += w.x * a[g]; acc[1][g] += w.y * a[g];
                        acc[2][g] += w.z * a[g]; acc[3][g] += w.w * a[g];
                    }
                }
                #pragma unroll
                for (int m = 1; m < 16; m <<= 1)
                    #pragma unroll
                    for (int r = 0; r < 4; ++r)
                        #pragma unroll
                        for (int g = 0; g < 8; ++g)
                            acc[r][g] += __shfl_xor(acc[r][g], m, 64);
                if (ks < 8) {
                    int g = ks;
                    #pragma unroll
                    for (int r = 0; r < 4; ++r) {
                        int c = tl * 4 + r;
                        sh_gh[g * 48 + c] = acc[r][g] + sh_bhh[c];
                    }
                }
            }
            cluster_bar(bcnt, bgen, target++);

            // ================= P2: stage z; ring=relu(W2 z); aggregate =================
            {
                const float* zp = zb + (size_t)(gb + sg) * CDIM + skb;
                float4 v0 = *(const float4*)zp, v1 = *(const float4*)(zp + 4);
                sh_act[(skb + 0) * AST + sg] = v0.x; sh_act[(skb + 1) * AST + sg] = v0.y;
                sh_act[(skb + 2) * AST + sg] = v0.z; sh_act[(skb + 3) * AST + sg] = v0.w;
                sh_act[(skb + 4) * AST + sg] = v1.x; sh_act[(skb + 5) * AST + sg] = v1.y;
                sh_act[(skb + 6) * AST + sg] = v1.z; sh_act[(skb + 7) * AST + sg] = v1.w;
            }
            if (tid < GW) sh_cnt[tid] = 0;
            __syncthreads();

            // W2 GEMM (cols 112..127) -> ring[prev&63]
            {
                const int tl = tid >> 5, ks = tid & 31;
                float acc0[8] = {}, acc1[8] = {};
                #pragma unroll
                for (int j = 0; j < 8; ++j) {
                    int k = ks + j * 32;
                    float2 w = *(const float2*)&sh_w[k * WST + 112 + tl * 2];
                    const float* ap = &sh_act[k * AST];
                    float2 a0 = *(const float2*)ap,       a1 = *(const float2*)(ap + 2);
                    float2 a2 = *(const float2*)(ap + 4), a3 = *(const float2*)(ap + 6);
                    float a[8] = {a0.x,a0.y,a1.x,a1.y,a2.x,a2.y,a3.x,a3.y};
                    #pragma unroll
                    for (int g = 0; g < 8; ++g) { acc0[g] += w.x * a[g]; acc1[g] += w.y * a[g]; }
                }
                #pragma unroll
                for (int m = 1; m < 32; m <<= 1)
                    #pragma unroll
                    for (int g = 0; g < 8; ++g) {
                        acc0[g] += __shfl_xor(acc0[g], m, 64);
                        acc1[g] += __shfl_xor(acc1[g], m, 64);
                    }
                if (ks < 8) {
                    int g = ks, c0 = tl * 2, slot = prev & 63;
                    float v0 = acc0[g] + sh_b2[c0];
                    float v1 = acc1[g] + sh_b2[c0 + 1];
                    ring_blk[(slot * GW + g) * CW + c0]     = v0 > 0.f ? v0 : 0.f;
                    ring_blk[(slot * GW + g) * CW + c0 + 1] = v1 > 0.f ? v1 : 0.f;
                }
            }
            // edge filter (direct from global, coalesced)
            for (int e = tid; e < K; e += TPB) {
                size_t off = (size_t)s * K + e;
                if (mskA[off] != 0.f) {
                    int g = gidA[off] - gb;
                    if ((unsigned)g < GW) {
                        int p = atomicAdd(&sh_cnt[g], 1);
                        if (p < CAP) sh_list[g * CAP + p] = srcA[off] & 63;
                    }
                }
            }
            __syncthreads();
            if (tid < 128) {
                int n = sh_cnt[cg]; if (n > CAP) n = CAP;
                float a = 0.f;
                for (int i = 0; i < n; ++i)
                    a += ring_blk[(sh_list[cg * CAP + i] * GW + cg) * CW + cc];
                agg[(size_t)(gb + cg) * CDIM + cbase + cc] = a;
            }
            cluster_bar(bcnt, bgen, target++);

            // ================= P3: stage agg; gi GEMM; gate combine =================
            {
                const float* ap = agg + (size_t)(gb + sg) * CDIM + skb;
                float4 v0 = *(const float4*)ap, v1 = *(const float4*)(ap + 4);
                sh_act[(skb + 0) * AST + sg] = v0.x; sh_act[(skb + 1) * AST + sg] = v0.y;
                sh_act[(skb + 2) * AST + sg] = v0.z; sh_act[(skb + 3) * AST + sg] = v0.w;
                sh_act[(skb + 4) * AST + sg] = v1.x; sh_act[(skb + 5) * AST + sg] = v1.y;
                sh_act[(skb + 6) * AST + sg] = v1.z; sh_act[(skb + 7) * AST + sg] = v1.w;
            }
            __syncthreads();
            if (tid < 192) {
                const int tl = tid >> 4, ks = tid & 15;
                float acc[4][8] = {};
                #pragma unroll 4
                for (int j = 0; j < 16; ++j) {
                    int k = ks + j * 16;
                    float4 w = *(const float4*)&sh_w[k * WST + tl * 4];
                    const float* ap = &sh_act[k * AST];
                    float2 a0 = *(const float2*)ap,       a1 = *(const float2*)(ap + 2);
                    float2 a2 = *(const float2*)(ap + 4), a3 = *(const float2*)(ap + 6);
                    float a[8] = {a0.x,a0.y,a1.x,a1.y,a2.x,a2.y,a3.x,a3.y};
                    #pragma unroll
                    for (int g = 0; g < 8; ++g) {
                        acc[0][g] += w.x * a[g]; acc[1][g] += w.y * a[g];
                        acc[2][g] += w.z * a[g]; acc[3][g] += w.w * a[g];
                    }
                }
                #pragma unroll
                for (int m = 1; m < 16; m <<= 1)
                    #pragma unroll
                    for (int r = 0; r < 4; ++r)
                        #pragma unroll
                        for (int g = 0; g < 8; ++g)
                            acc[r][g] += __shfl_xor(acc[r][g], m, 64);
                if (ks < 8) {
                    int g = ks;
                    #pragma unroll
                    for (int r = 0; r < 4; ++r) {
                        int c = tl * 4 + r;
                        sh_gi[g * 48 + c] = acc[r][g] + sh_bih[c];
                    }
                }
            }
            __syncthreads();
            if (tid < 128) {
                float ir = sh_gi[cg * 48 + cc], iz = sh_gi[cg * 48 + 16 + cc], in_ = sh_gi[cg * 48 + 32 + cc];
                float hr = sh_gh[cg * 48 + cc], hz = sh_gh[cg * 48 + 16 + cc], hn  = sh_gh[cg * 48 + 32 + cc];
                float hold = sh_hold[(cbase + cc) * AST + cg];
                float r  = 1.f / (1.f + expf(-(ir + hr)));
                float z_ = 1.f / (1.f + expf(-(iz + hz)));
                float nn = tanhf(in_ + r * hn);
                keep0 = (1.f - z_) * nn + z_ * hold;
                hnew[(size_t)(gb + cg) * CDIM + cbase + cc] = keep0;
            }
            cluster_bar(bcnt, bgen, target++);
        }
    }
    if (tid < 128)
        hx[((size_t)(gb + cg) * NPER + 0) * CDIM + cbase + cc] = keep0;
}

// ---------------- fallback: round-1 structure, fp32 LDS ring (known-correct, slow) ----------------
__global__ __launch_bounds__(512)
void gnn_fallback(const float* __restrict__ x,
                  const float* __restrict__ W1, const float* __restrict__ b1,
                  const float* __restrict__ W2, const float* __restrict__ b2,
                  const float* __restrict__ w_ih, const float* __restrict__ b_ih,
                  const float* __restrict__ w_hh, const float* __restrict__ b_hh,
                  const int* __restrict__ src_f, const int* __restrict__ gid_f,
                  const float* __restrict__ msk_f,
                  const int* __restrict__ src_b, const int* __restrict__ gid_b,
                  const float* __restrict__ msk_b,
                  int Kf, int Kb, float* __restrict__ hx)
{
    const int b = blockIdx.x, t = threadIdx.x;
    __shared__ float sh_ring[64 * CDIM];
    __shared__ float sh_agg[CDIM], sh_hold[CDIM], sh_hnew[CDIM], sh_h1[CDIM];
    __shared__ float sh_gi[3 * CDIM], sh_gh[3 * CDIM];
    __shared__ int   sh_list[256];
    __shared__ int   sh_cnt;
    const size_t base = (size_t)b * NPER * CDIM;
    {
        const float4* x4 = (const float4*)(x + base);
        float4* h4 = (float4*)(hx + base);
        for (int i = t; i < NPER * CDIM / 4; i += 512) h4[i] = x4[i];
    }
    if (t == 0) sh_cnt = 0;
    __syncthreads();
    for (int pass = 0; pass < 2; ++pass) {
        const int* srcA = pass ? src_b : src_f;
        const int* gidA = pass ? gid_b : gid_f;
        const float* mskA = pass ? msk_b : msk_f;
        const int K = pass ? Kb : Kf;
        for (int step = 0; step < NPER; ++step) {
            const int node = pass ? (NPER - 1 - step) : step;
            if (t < CDIM / 4)
                ((float4*)sh_hold)[t] = ((const float4*)(hx + base + (size_t)node * CDIM))[t];
            for (int k = t; k < K; k += 512) {
                size_t off = (size_t)step * K + k;
                if (mskA[off] != 0.f && gidA[off] == b) {
                    int p = atomicAdd(&sh_cnt, 1);
                    if (p < 256) sh_list[p] = srcA[off] & 63;
                }
            }
            __syncthreads();
            int cnt = sh_cnt; if (cnt > 256) cnt = 256;
            if (t < CDIM) {
                float a = 0.f;
                for (int e = 0; e < cnt; ++e) a += sh_ring[sh_list[e] * CDIM + t];
                sh_agg[t] = a;
            }
            __syncthreads();
            #pragma unroll
            for (int d = 0; d < 3; ++d) {
                const int idx = t + d * 512;
                const float *wrow, *inv; float bias; float* outp;
                if (idx < 3 * CDIM) { wrow = w_ih + (size_t)idx * CDIM; inv = sh_agg; bias = b_ih[idx]; outp = &sh_gi[idx]; }
                else { int r = idx - 3 * CDIM; wrow = w_hh + (size_t)r * CDIM; inv = sh_hold; bias = b_hh[r]; outp = &sh_gh[r]; }
                float acc = 0.f;
                const float4* w4 = (const float4*)wrow; const float4* i4 = (const float4*)inv;
                #pragma unroll 8
                for (int j = 0; j < CDIM / 4; ++j) {
                    float4 w = w4[j], v = i4[j];
                    acc += w.x * v.x + w.y * v.y + w.z * v.z + w.w * v.w;
                }
                *outp = acc + bias;
            }
            __syncthreads();
            if (t < CDIM) {
                float ir = sh_gi[t], iz = sh_gi[t + CDIM], in_ = sh_gi[t + 2 * CDIM];
                float hr = sh_gh[t], hz = sh_gh[t + CDIM], hn = sh_gh[t + 2 * CDIM];
                float r = 1.f / (1.f + expf(-(ir + hr)));
                float z = 1.f / (1.f + expf(-(iz + hz)));
                float n = tanhf(in_ + r * hn);
                float hv = (1.f - z) * n + z * sh_hold[t];
                sh_hnew[t] = hv;
                hx[base + (size_t)node * CDIM + t] = hv;
            }
            if (t == 511) sh_cnt = 0;
            __syncthreads();
            if (t < CDIM) {
                const float4* w4 = (const float4*)(W1 + (size_t)t * CDIM);
                const float4* i4 = (const float4*)sh_hnew;
                float acc = 0.f;
                #pragma unroll 8
                for (int j = 0; j < CDIM / 4; ++j) {
                    float4 w = w4[j], v = i4[j];
                    acc += w.x * v.x + w.y * v.y + w.z * v.z + w.w * v.w;
                }
                acc += b1[t];
                sh_h1[t] = acc > 0.f ? acc : 0.f;
            }
            __syncthreads();
            if (t < CDIM) {
                const float4* w4 = (const float4*)(W2 + (size_t)t * CDIM);
                const float4* i4 = (const float4*)sh_h1;
                float acc = 0.f;
                #pragma unroll 8
                for (int j = 0; j < CDIM / 4; ++j) {
                    float4 w = w4[j], v = i4[j];
                    acc += w.x * v.x + w.y * v.y + w.z * v.z + w.w * v.w;
                }
                acc += b2[t];
                sh_ring[(node & 63) * CDIM + t] = acc > 0.f ? acc : 0.f;
            }
            __syncthreads();
        }
    }
}

extern "C" void kernel_launch(void* const* d_in, const int* in_sizes, int n_in,
                              void* d_out, int out_size, void* d_ws, size_t ws_size,
                              hipStream_t stream) {
    const float* x    = (const float*)d_in[0];
    const float* W1   = (const float*)d_in[1];
    const float* b1   = (const float*)d_in[2];
    const float* W2   = (const float*)d_in[3];
    const float* b2   = (const float*)d_in[4];
    const float* w_ih = (const float*)d_in[5];
    const float* b_ih = (const float*)d_in[6];
    const float* w_hh = (const float*)d_in[7];
    const float* b_hh = (const float*)d_in[8];
    const int*   src_f = (const int*)d_in[9];
    const int*   gid_f = (const int*)d_in[10];
    const float* msk_f = (const float*)d_in[11];
    const int*   src_b = (const int*)d_in[12];
    const int*   gid_b = (const int*)d_in[13];
    const float* msk_b = (const float*)d_in[14];

    const int Kf = in_sizes[9]  / NPER;
    const int Kb = in_sizes[12] / NPER;
    float* hx = (float*)d_out;

    char* ws = (char*)d_ws;
    // layout: bar 4KB | hnew 64KB | z 64KB | agg 64KB | ring 4MB
    const size_t need = 4096 + 3 * (size_t)BG * CDIM * 4 + (size_t)NB * 64 * GW * CW * 4;
    if (ws_size >= need) {
        int*   bar  = (int*)ws;
        float* hnew = (float*)(ws + 4096);
        float* zb   = hnew + BG * CDIM;
        float* agg  = zb + BG * CDIM;
        float* ring = agg + BG * CDIM;
        init_bar<<<1, 512, 0, stream>>>(bar);
        gnn_fp32<<<NB, TPB, 0, stream>>>(
            x, W1, b1, W2, b2, w_ih, b_ih, w_hh, b_hh,
            src_f, gid_f, msk_f, src_b, gid_b, msk_b,
            Kf, Kb, hx, hnew, zb, agg, ring, bar);
    } else {
        gnn_fallback<<<BG, 512, 0, stream>>>(
            x, W1, b1, W2, b2, w_ih, b_ih, w_hh, b_hh,
            src_f, gid_f, msk_f, src_b, gid_b, msk_b,
            Kf, Kb, hx);
    }
}

// Round 4
// 20351.921 us; speedup vs baseline: 3.0137x; 1.6572x over previous
//
#include <hip/hip_runtime.h>

#define NPER 512
#define CDIM 256
#define BG   64
#define NB   128
#define TPB  256
#define MPC  16     // members (blocks) per cluster
#define GW   8      // graphs per cluster
#define CW   16     // channels per member
#define WST  258    // col-major weight stride (256 + 2): bank stride 2 -> free
#define AST  10     // k-major activation stride (8 graphs + 2 pad)
#define CAP  64

__global__ void init_bar(int* bar) { if (threadIdx.x < 512) bar[threadIdx.x] = 0; }

__device__ __forceinline__ float ld_sc(const float* p) {
    return __hip_atomic_load((float*)p, __ATOMIC_RELAXED, __HIP_MEMORY_SCOPE_AGENT);
}
__device__ __forceinline__ void st_sc(float* p, float v) {
    __hip_atomic_store(p, v, __ATOMIC_RELAXED, __HIP_MEMORY_SCOPE_AGENT);
}

// Fence-free cluster barrier. __syncthreads() drains each wave's vm ops
// (sc1 stores are then at the LLC coherence point); the monotonic counter
// and gen flag are LLC-homed atomics, so arrival order == data visibility.
__device__ __forceinline__ void cluster_bar(int* cnt, int* gen, int target) {
    __syncthreads();
    if (threadIdx.x == 0) {
        int prev = __hip_atomic_fetch_add(cnt, 1, __ATOMIC_RELAXED, __HIP_MEMORY_SCOPE_AGENT);
        if (prev == target * MPC - 1) {
            __hip_atomic_store(gen, target, __ATOMIC_RELAXED, __HIP_MEMORY_SCOPE_AGENT);
        } else {
            while (__hip_atomic_load(gen, __ATOMIC_RELAXED, __HIP_MEMORY_SCOPE_AGENT) < target)
                __builtin_amdgcn_s_sleep(1);
        }
    }
    __syncthreads();
}

__global__ __launch_bounds__(TPB, 1)
void gnn_fp32(const float* __restrict__ x,
              const float* __restrict__ W1g, const float* __restrict__ b1g,
              const float* __restrict__ W2g, const float* __restrict__ b2g,
              const float* __restrict__ wihg, const float* __restrict__ bihg,
              const float* __restrict__ whhg, const float* __restrict__ bhhg,
              const int* __restrict__ src_f, const int* __restrict__ gid_f,
              const float* __restrict__ msk_f,
              const int* __restrict__ src_b, const int* __restrict__ gid_b,
              const float* __restrict__ msk_b,
              int Kf, int Kb,
              float* __restrict__ hx,
              float* __restrict__ hnew, float* __restrict__ zb,
              float* __restrict__ agg, float* __restrict__ ring,
              int* bar)
{
    __shared__ float sh_w[128 * WST];    // col-major rows: 0-47 wih, 48-95 whh, 96-111 W1, 112-127 W2
    __shared__ float sh_act[256 * AST];
    __shared__ float sh_hold[256 * AST];
    __shared__ float sh_gi[GW * 48];
    __shared__ float sh_gh[GW * 48];
    __shared__ int   sh_list[GW * CAP];
    __shared__ int   sh_cnt[GW];
    __shared__ float sh_bih[48], sh_bhh[48], sh_b1[CW], sh_b2[CW];

    const int tid   = threadIdx.x;
    const int cl    = blockIdx.x & 7;
    const int mb    = blockIdx.x >> 3;
    const int gb    = cl * GW;
    const int cbase = mb * CW;

    int* bcnt = bar + cl * 64;
    int* bgen = bar + cl * 64 + 16;
    float* ring_blk = ring + (size_t)blockIdx.x * 64 * GW * CW;

    // ---- stage weights col-major into LDS, once ----
    for (int e = tid; e < 128 * 256; e += TPB) {
        int r = e >> 8, k = e & 255;
        const float* sp; int grow;
        if (r < 48)       { sp = wihg; grow = (r >> 4) * CDIM + cbase + (r & 15); }
        else if (r < 96)  { sp = whhg; grow = ((r - 48) >> 4) * CDIM + cbase + ((r - 48) & 15); }
        else if (r < 112) { sp = W1g;  grow = cbase + (r - 96); }
        else              { sp = W2g;  grow = cbase + (r - 112); }
        sh_w[r * WST + k] = sp[(size_t)grow * CDIM + k];
    }
    if (tid < 48) {
        sh_bih[tid] = bihg[(tid >> 4) * CDIM + cbase + (tid & 15)];
        sh_bhh[tid] = bhhg[(tid >> 4) * CDIM + cbase + (tid & 15)];
    } else if (tid < 64) {
        sh_b1[tid - 48] = b1g[cbase + tid - 48];
        sh_b2[tid - 48] = b2g[cbase + tid - 48];
    }
    __syncthreads();

    int target = 1;
    float keep0 = 0.f;
    const int cg = tid >> 4;
    const int cc = tid & 15;

    for (int pass = 0; pass < 2; ++pass) {
        const int* srcA   = pass ? src_b : src_f;
        const int* gidA   = pass ? gid_b : gid_f;
        const float* mskA = pass ? msk_b : msk_f;
        const int K = pass ? Kb : Kf;

        for (int s = 0; s < NPER; ++s) {
            const int node = pass ? (NPER - 1 - s) : s;
            const bool has_prev = !(pass == 0 && s == 0);
            const int prev = (s > 0) ? (pass ? node + 1 : node - 1) : (NPER - 1);

            // ======= P1: deferred hx write; stage hnew + h_old; z = relu(W1 hnew); gh GEMM =======
            if (has_prev && tid < 128)
                st_sc(&hx[((size_t)(gb + cg) * NPER + prev) * CDIM + cbase + cc], keep0);
            #pragma unroll
            for (int j = 0; j < 8; ++j) {           // hnew -> sh_act (sc1)
                int e = tid + j * TPB, g = e >> 8, k = e & 255;
                sh_act[k * AST + g] = ld_sc(&hnew[(size_t)(gb + g) * CDIM + k]);
            }
            if (pass == 0) {                        // h_old = x (read-only: cached loads)
                int sg = tid & 7, skb = (tid >> 3) << 3;
                const float* op = x + ((size_t)(gb + sg) * NPER + node) * CDIM + skb;
                float4 h0 = *(const float4*)op, h1 = *(const float4*)(op + 4);
                float* d = &sh_hold[skb * AST + sg];
                d[0] = h0.x; d[AST] = h0.y; d[2*AST] = h0.z; d[3*AST] = h0.w;
                d[4*AST] = h1.x; d[5*AST] = h1.y; d[6*AST] = h1.z; d[7*AST] = h1.w;
            } else {
                #pragma unroll
                for (int j = 0; j < 8; ++j) {
                    int e = tid + j * TPB, g = e >> 8, k = e & 255;
                    float v = (s == 0) ? ld_sc(&hnew[(size_t)(gb + g) * CDIM + k])
                                       : ld_sc(&hx[((size_t)(gb + g) * NPER + node) * CDIM + k]);
                    sh_hold[k * AST + g] = v;
                }
            }
            __syncthreads();

            {   // W1 GEMM (rows 96..111) -> zb slice
                const int tl = tid >> 5, ks = tid & 31;
                const float* wr0 = &sh_w[(96 + tl * 2) * WST];
                const float* wr1 = wr0 + WST;
                float acc0[8] = {}, acc1[8] = {};
                #pragma unroll
                for (int j = 0; j < 8; ++j) {
                    int k = ks + j * 32;
                    float w0 = wr0[k], w1 = wr1[k];
                    const float* ap = &sh_act[k * AST];
                    #pragma unroll
                    for (int g = 0; g < 8; ++g) {
                        float a = ap[g];
                        acc0[g] += w0 * a; acc1[g] += w1 * a;
                    }
                }
                #pragma unroll
                for (int m = 1; m < 32; m <<= 1)
                    #pragma unroll
                    for (int g = 0; g < 8; ++g) {
                        acc0[g] += __shfl_xor(acc0[g], m, 64);
                        acc1[g] += __shfl_xor(acc1[g], m, 64);
                    }
                if (ks < 8) {
                    int g = ks, c0 = tl * 2;
                    float v0 = acc0[g] + sh_b1[c0];
                    float v1 = acc1[g] + sh_b1[c0 + 1];
                    st_sc(&zb[(size_t)(gb + g) * CDIM + cbase + c0],     v0 > 0.f ? v0 : 0.f);
                    st_sc(&zb[(size_t)(gb + g) * CDIM + cbase + c0 + 1], v1 > 0.f ? v1 : 0.f);
                }
            }
            if (tid < 192) {  // gh GEMM (rows 48..95) -> sh_gh
                const int tl = tid >> 4, ks = tid & 15;
                const float* wr = &sh_w[(48 + tl * 4) * WST];
                float acc[4][8] = {};
                #pragma unroll 4
                for (int j = 0; j < 16; ++j) {
                    int k = ks + j * 16;
                    float w0 = wr[k], w1 = wr[WST + k], w2 = wr[2 * WST + k], w3 = wr[3 * WST + k];
                    const float* ap = &sh_hold[k * AST];
                    #pragma unroll
                    for (int g = 0; g < 8; ++g) {
                        float a = ap[g];
                        acc[0][g] += w0 * a; acc[1][g] += w1 * a;
                        acc[2][g] += w2 * a; acc[3][g] += w3 * a;
                    }
                }
                #pragma unroll
                for (int m = 1; m < 16; m <<= 1)
                    #pragma unroll
                    for (int r = 0; r < 4; ++r)
                        #pragma unroll
                        for (int g = 0; g < 8; ++g)
                            acc[r][g] += __shfl_xor(acc[r][g], m, 64);
                if (ks < 8) {
                    int g = ks;
                    #pragma unroll
                    for (int r = 0; r < 4; ++r)
                        sh_gh[g * 48 + tl * 4 + r] = acc[r][g] + sh_bhh[tl * 4 + r];
                }
            }
            cluster_bar(bcnt, bgen, target++);

            // ======= P2: stage z; ring = relu(W2 z); edge filter; aggregate =======
            #pragma unroll
            for (int j = 0; j < 8; ++j) {
                int e = tid + j * TPB, g = e >> 8, k = e & 255;
                sh_act[k * AST + g] = ld_sc(&zb[(size_t)(gb + g) * CDIM + k]);
            }
            if (tid < GW) sh_cnt[tid] = 0;
            __syncthreads();

            {   // W2 GEMM (rows 112..127) -> ring[prev & 63] (block-private, cached)
                const int tl = tid >> 5, ks = tid & 31;
                const float* wr0 = &sh_w[(112 + tl * 2) * WST];
                const float* wr1 = wr0 + WST;
                float acc0[8] = {}, acc1[8] = {};
                #pragma unroll
                for (int j = 0; j < 8; ++j) {
                    int k = ks + j * 32;
                    float w0 = wr0[k], w1 = wr1[k];
                    const float* ap = &sh_act[k * AST];
                    #pragma unroll
                    for (int g = 0; g < 8; ++g) {
                        float a = ap[g];
                        acc0[g] += w0 * a; acc1[g] += w1 * a;
                    }
                }
                #pragma unroll
                for (int m = 1; m < 32; m <<= 1)
                    #pragma unroll
                    for (int g = 0; g < 8; ++g) {
                        acc0[g] += __shfl_xor(acc0[g], m, 64);
                        acc1[g] += __shfl_xor(acc1[g], m, 64);
                    }
                if (ks < 8) {
                    int g = ks, c0 = tl * 2, slot = prev & 63;
                    float v0 = acc0[g] + sh_b2[c0];
                    float v1 = acc1[g] + sh_b2[c0 + 1];
                    ring_blk[(slot * GW + g) * CW + c0]     = v0 > 0.f ? v0 : 0.f;
                    ring_blk[(slot * GW + g) * CW + c0 + 1] = v1 > 0.f ? v1 : 0.f;
                }
            }
            for (int e = tid; e < K; e += TPB) {   // edge filter (L2-warm cached loads)
                size_t off = (size_t)s * K + e;
                if (mskA[off] != 0.f) {
                    int g = gidA[off] - gb;
                    if ((unsigned)g < GW) {
                        int p = atomicAdd(&sh_cnt[g], 1);
                        if (p < CAP) sh_list[g * CAP + p] = srcA[off] & 63;
                    }
                }
            }
            __syncthreads();
            if (tid < 128) {
                int n = sh_cnt[cg]; if (n > CAP) n = CAP;
                float a = 0.f;
                for (int i = 0; i < n; ++i)
                    a += ring_blk[(sh_list[cg * CAP + i] * GW + cg) * CW + cc];
                st_sc(&agg[(size_t)(gb + cg) * CDIM + cbase + cc], a);
            }
            cluster_bar(bcnt, bgen, target++);

            // ======= P3: stage agg; gi GEMM; gate combine -> hnew =======
            #pragma unroll
            for (int j = 0; j < 8; ++j) {
                int e = tid + j * TPB, g = e >> 8, k = e & 255;
                sh_act[k * AST + g] = ld_sc(&agg[(size_t)(gb + g) * CDIM + k]);
            }
            __syncthreads();
            if (tid < 192) {  // gi GEMM (rows 0..47) -> sh_gi
                const int tl = tid >> 4, ks = tid & 15;
                const float* wr = &sh_w[(tl * 4) * WST];
                float acc[4][8] = {};
                #pragma unroll 4
                for (int j = 0; j < 16; ++j) {
                    int k = ks + j * 16;
                    float w0 = wr[k], w1 = wr[WST + k], w2 = wr[2 * WST + k], w3 = wr[3 * WST + k];
                    const float* ap = &sh_act[k * AST];
                    #pragma unroll
                    for (int g = 0; g < 8; ++g) {
                        float a = ap[g];
                        acc[0][g] += w0 * a; acc[1][g] += w1 * a;
                        acc[2][g] += w2 * a; acc[3][g] += w3 * a;
                    }
                }
                #pragma unroll
                for (int m = 1; m < 16; m <<= 1)
                    #pragma unroll
                    for (int r = 0; r < 4; ++r)
                        #pragma unroll
                        for (int g = 0; g < 8; ++g)
                            acc[r][g] += __shfl_xor(acc[r][g], m, 64);
                if (ks < 8) {
                    int g = ks;
                    #pragma unroll
                    for (int r = 0; r < 4; ++r)
                        sh_gi[g * 48 + tl * 4 + r] = acc[r][g] + sh_bih[tl * 4 + r];
                }
            }
            __syncthreads();
            if (tid < 128) {
                float ir = sh_gi[cg * 48 + cc], iz = sh_gi[cg * 48 + 16 + cc], in_ = sh_gi[cg * 48 + 32 + cc];
                float hr = sh_gh[cg * 48 + cc], hz = sh_gh[cg * 48 + 16 + cc], hn  = sh_gh[cg * 48 + 32 + cc];
                float hold = sh_hold[(cbase + cc) * AST + cg];
                float r  = 1.f / (1.f + expf(-(ir + hr)));
                float z_ = 1.f / (1.f + expf(-(iz + hz)));
                float nn = tanhf(in_ + r * hn);
                keep0 = (1.f - z_) * nn + z_ * hold;
                st_sc(&hnew[(size_t)(gb + cg) * CDIM + cbase + cc], keep0);
            }
            cluster_bar(bcnt, bgen, target++);
        }
    }
    if (tid < 128)
        st_sc(&hx[((size_t)(gb + cg) * NPER + 0) * CDIM + cbase + cc], keep0);
}

// ---------------- fallback (round-1 structure, known-correct) ----------------
__global__ __launch_bounds__(512)
void gnn_fallback(const float* __restrict__ x,
                  const float* __restrict__ W1, const float* __restrict__ b1,
                  const float* __restrict__ W2, const float* __restrict__ b2,
                  const float* __restrict__ w_ih, const float* __restrict__ b_ih,
                  const float* __restrict__ w_hh, const float* __restrict__ b_hh,
                  const int* __restrict__ src_f, const int* __restrict__ gid_f,
                  const float* __restrict__ msk_f,
                  const int* __restrict__ src_b, const int* __restrict__ gid_b,
                  const float* __restrict__ msk_b,
                  int Kf, int Kb, float* __restrict__ hx)
{
    const int b = blockIdx.x, t = threadIdx.x;
    __shared__ float sh_ring[64 * CDIM];
    __shared__ float sh_agg[CDIM], sh_hold[CDIM], sh_hnew[CDIM], sh_h1[CDIM];
    __shared__ float sh_gi[3 * CDIM], sh_gh[3 * CDIM];
    __shared__ int   sh_list[256];
    __shared__ int   sh_cnt;
    const size_t base = (size_t)b * NPER * CDIM;
    {
        const float4* x4 = (const float4*)(x + base);
        float4* h4 = (float4*)(hx + base);
        for (int i = t; i < NPER * CDIM / 4; i += 512) h4[i] = x4[i];
    }
    if (t == 0) sh_cnt = 0;
    __syncthreads();
    for (int pass = 0; pass < 2; ++pass) {
        const int* srcA = pass ? src_b : src_f;
        const int* gidA = pass ? gid_b : gid_f;
        const float* mskA = pass ? msk_b : msk_f;
        const int K = pass ? Kb : Kf;
        for (int step = 0; step < NPER; ++step) {
            const int node = pass ? (NPER - 1 - step) : step;
            if (t < CDIM / 4)
                ((float4*)sh_hold)[t] = ((const float4*)(hx + base + (size_t)node * CDIM))[t];
            for (int k = t; k < K; k += 512) {
                size_t off = (size_t)step * K + k;
                if (mskA[off] != 0.f && gidA[off] == b) {
                    int p = atomicAdd(&sh_cnt, 1);
                    if (p < 256) sh_list[p] = srcA[off] & 63;
                }
            }
            __syncthreads();
            int cnt = sh_cnt; if (cnt > 256) cnt = 256;
            if (t < CDIM) {
                float a = 0.f;
                for (int e = 0; e < cnt; ++e) a += sh_ring[sh_list[e] * CDIM + t];
                sh_agg[t] = a;
            }
            __syncthreads();
            #pragma unroll
            for (int d = 0; d < 3; ++d) {
                const int idx = t + d * 512;
                const float *wrow, *inv; float bias; float* outp;
                if (idx < 3 * CDIM) { wrow = w_ih + (size_t)idx * CDIM; inv = sh_agg; bias = b_ih[idx]; outp = &sh_gi[idx]; }
                else { int r = idx - 3 * CDIM; wrow = w_hh + (size_t)r * CDIM; inv = sh_hold; bias = b_hh[r]; outp = &sh_gh[r]; }
                float acc = 0.f;
                const float4* w4 = (const float4*)wrow; const float4* i4 = (const float4*)inv;
                #pragma unroll 8
                for (int j = 0; j < CDIM / 4; ++j) {
                    float4 w = w4[j], v = i4[j];
                    acc += w.x * v.x + w.y * v.y + w.z * v.z + w.w * v.w;
                }
                *outp = acc + bias;
            }
            __syncthreads();
            if (t < CDIM) {
                float ir = sh_gi[t], iz = sh_gi[t + CDIM], in_ = sh_gi[t + 2 * CDIM];
                float hr = sh_gh[t], hz = sh_gh[t + CDIM], hn = sh_gh[t + 2 * CDIM];
                float r = 1.f / (1.f + expf(-(ir + hr)));
                float z = 1.f / (1.f + expf(-(iz + hz)));
                float n = tanhf(in_ + r * hn);
                float hv = (1.f - z) * n + z * sh_hold[t];
                sh_hnew[t] = hv;
                hx[base + (size_t)node * CDIM + t] = hv;
            }
            if (t == 511) sh_cnt = 0;
            __syncthreads();
            if (t < CDIM) {
                const float4* w4 = (const float4*)(W1 + (size_t)t * CDIM);
                const float4* i4 = (const float4*)sh_hnew;
                float acc = 0.f;
                #pragma unroll 8
                for (int j = 0; j < CDIM / 4; ++j) {
                    float4 w = w4[j], v = i4[j];
                    acc += w.x * v.x + w.y * v.y + w.z * v.z + w.w * v.w;
                }
                acc += b1[t];
                sh_h1[t] = acc > 0.f ? acc : 0.f;
            }
            __syncthreads();
            if (t < CDIM) {
                const float4* w4 = (const float4*)(W2 + (size_t)t * CDIM);
                const float4* i4 = (const float4*)sh_h1;
                float acc = 0.f;
                #pragma unroll 8
                for (int j = 0; j < CDIM / 4; ++j) {
                    float4 w = w4[j], v = i4[j];
                    acc += w.x * v.x + w.y * v.y + w.z * v.z + w.w * v.w;
                }
                acc += b2[t];
                sh_ring[(node & 63) * CDIM + t] = acc > 0.f ? acc : 0.f;
            }
            __syncthreads();
        }
    }
}

extern "C" void kernel_launch(void* const* d_in, const int* in_sizes, int n_in,
                              void* d_out, int out_size, void* d_ws, size_t ws_size,
                              hipStream_t stream) {
    const float* x    = (const float*)d_in[0];
    const float* W1   = (const float*)d_in[1];
    const float* b1   = (const float*)d_in[2];
    const float* W2   = (const float*)d_in[3];
    const float* b2   = (const float*)d_in[4];
    const float* w_ih = (const float*)d_in[5];
    const float* b_ih = (const float*)d_in[6];
    const float* w_hh = (const float*)d_in[7];
    const float* b_hh = (const float*)d_in[8];
    const int*   src_f = (const int*)d_in[9];
    const int*   gid_f = (const int*)d_in[10];
    const float* msk_f = (const float*)d_in[11];
    const int*   src_b = (const int*)d_in[12];
    const int*   gid_b = (const int*)d_in[13];
    const float* msk_b = (const float*)d_in[14];

    const int Kf = in_sizes[9]  / NPER;
    const int Kb = in_sizes[12] / NPER;
    float* hx = (float*)d_out;

    char* ws = (char*)d_ws;
    const size_t need = 4096 + 3 * (size_t)BG * CDIM * 4 + (size_t)NB * 64 * GW * CW * 4;
    if (ws_size >= need) {
        int*   bar  = (int*)ws;
        float* hnew = (float*)(ws + 4096);
        float* zb   = hnew + BG * CDIM;
        float* agg  = zb + BG * CDIM;
        float* ring = agg + BG * CDIM;
        init_bar<<<1, 512, 0, stream>>>(bar);
        gnn_fp32<<<NB, TPB, 0, stream>>>(
            x, W1, b1, W2, b2, w_ih, b_ih, w_hh, b_hh,
            src_f, gid_f, msk_f, src_b, gid_b, msk_b,
            Kf, Kb, hx, hnew, zb, agg, ring, bar);
    } else {
        gnn_fallback<<<BG, 512, 0, stream>>>(
            x, W1, b1, W2, b2, w_ih, b_ih, w_hh, b_hh,
            src_f, gid_f, msk_f, src_b, gid_b, msk_b,
            Kf, Kb, hx);
    }
}